// Round 8
// baseline (83.464 us; speedup 1.0000x reference)
//
#include <hip/hip_runtime.h>
#include <hip/hip_bf16.h>
#include <stdint.h>

#define HID 768

typedef short bf16x8 __attribute__((ext_vector_type(8)));
typedef unsigned short ushort8_t __attribute__((ext_vector_type(8)));
typedef float f32x4 __attribute__((ext_vector_type(4)));

// packed f32x2 -> bf16x2 (compiler emits v_cvt_pk_bf16_f32)
__device__ __forceinline__ unsigned int pack2bf(float x, float y) {
    __hip_bfloat162 h = __float22bfloat162_rn(make_float2(x, y));
    return *reinterpret_cast<unsigned int*>(&h);
}
__device__ __forceinline__ unsigned short f2bf1(float x) {
    __hip_bfloat16 h = __float2bfloat16(x);
    return *reinterpret_cast<unsigned short*>(&h);
}

// async global->LDS, 16B per lane; lds dest = wave-uniform base + lane*16
__device__ __forceinline__ void gload_lds16(const void* g, void* l) {
    __builtin_amdgcn_global_load_lds(
        (const __attribute__((address_space(1))) unsigned int*)g,
        (__attribute__((address_space(3))) unsigned int*)l, 16, 0, 0);
}

// ---------------- merged transpose+cast: 4 regions, f32 [R][C] -> bf16 [C][R] ----
__global__ void prep_k(const float* __restrict__ W1,
                       const float* __restrict__ W2,
                       const float* __restrict__ W3,
                       unsigned short* __restrict__ W1x,
                       unsigned short* __restrict__ W2t,
                       unsigned short* __restrict__ W3t) {
    __shared__ float t[32][33];
    int b = blockIdx.x;
    const float* in; unsigned short* op; int R, C, bx, by;
    if (b < 576)       { in = W1;           op = W1x;           R = 768; C = 768; bx = b % 24;        by = b / 24; }
    else if (b < 1152) { in = W1 + 768*768; op = W1x + 768*768; R = 768; C = 768; bx = (b-576) % 24;  by = (b-576) / 24; }
    else if (b < 1440) { in = W2;           op = W2t;           R = 768; C = 384; bx = (b-1152) % 12; by = (b-1152) / 12; }
    else               { in = W3;           op = W3t;           R = 384; C = 128; bx = (b-1440) % 4;  by = (b-1440) / 4; }
    int c0 = bx * 32, r0 = by * 32;
    int tx = threadIdx.x, ty = threadIdx.y;   // 32 x 8
    #pragma unroll
    for (int k = 0; k < 4; ++k)
        t[ty + 8*k][tx] = in[(size_t)(r0 + ty + 8*k) * C + c0 + tx];
    __syncthreads();
    #pragma unroll
    for (int k = 0; k < 4; ++k)
        op[(size_t)(c0 + ty + 8*k) * R + r0 + tx] = f2bf1(t[tx][ty + 8*k]);
}

// ---------------- AB = feat @ W1x^T (+b1 on A half) : M=256, N=1536, K=768 ------
// 96 blocks of 64m x 64n; 4 waves, wave n-band = wid*16
__launch_bounds__(256, 2)
__global__ void ab_gemm_k(const float* __restrict__ F,
                          const unsigned short* __restrict__ W,
                          const float* __restrict__ b1,
                          float* __restrict__ AB) {
    __shared__ alignas(1024) unsigned short fl[2][64*72];   // 18,432 B
    __shared__ alignas(1024) unsigned short wl[2][64*64];   // 16,384 B (swizzled)
    int tid = threadIdx.x;
    int lane = tid & 63, wid = tid >> 6;   // 4 waves
    int n0 = blockIdx.x * 64, m0 = blockIdx.y * 64;
    f32x4 acc[4] = {};
    float4 rf[2][2];

    #pragma unroll
    for (int s = 0; s < 2; ++s) {          // W tile 64x64 -> 8 chunks of 1024B
        int chunk = wid*2 + s;
        int row = chunk*8 + (lane>>3);
        int cg = (lane&7) ^ (row&7);
        gload_lds16(W + (size_t)(n0 + row)*HID + cg*8, (char*)wl[0] + chunk*1024);
    }
    #pragma unroll
    for (int s = 0; s < 2; ++s) {          // F tile 64x64 f32
        int idx = tid + s*256;
        int r = idx >> 3, c8 = idx & 7;
        const float4* src = (const float4*)(F + (size_t)(m0 + r)*HID + c8*8);
        rf[s][0] = src[0]; rf[s][1] = src[1];
    }
    #pragma unroll
    for (int s = 0; s < 2; ++s) {
        int idx = tid + s*256;
        int r = idx >> 3, c8 = idx & 7;
        unsigned int us32[4] = { pack2bf(rf[s][0].x, rf[s][0].y), pack2bf(rf[s][0].z, rf[s][0].w),
                                 pack2bf(rf[s][1].x, rf[s][1].y), pack2bf(rf[s][1].z, rf[s][1].w) };
        *(ushort8_t*)(fl[0] + r*72 + c8*8) = *(ushort8_t*)us32;
    }
    __syncthreads();

    for (int t = 0; t < 12; ++t) {
        int cur = t & 1;
        if (t < 11) {
            int kk = (t+1) * 64;
            #pragma unroll
            for (int s = 0; s < 2; ++s) {
                int chunk = wid*2 + s;
                int row = chunk*8 + (lane>>3);
                int cg = (lane&7) ^ (row&7);
                gload_lds16(W + (size_t)(n0 + row)*HID + kk + cg*8, (char*)wl[cur^1] + chunk*1024);
            }
            #pragma unroll
            for (int s = 0; s < 2; ++s) {
                int idx = tid + s*256;
                int r = idx >> 3, c8 = idx & 7;
                const float4* src = (const float4*)(F + (size_t)(m0 + r)*HID + kk + c8*8);
                rf[s][0] = src[0]; rf[s][1] = src[1];
            }
        }
        __builtin_amdgcn_s_setprio(1);
        #pragma unroll
        for (int ks = 0; ks < 2; ++ks) {
            bf16x8 a[4], b;
            #pragma unroll
            for (int fm = 0; fm < 4; ++fm)
                a[fm] = *(const bf16x8*)(fl[cur] + (fm*16 + (lane&15))*72 + ks*32 + (lane>>4)*8);
            {
                int n = wid*16 + (lane&15);
                int g = ks*4 + (lane>>4);
                b = *(const bf16x8*)(wl[cur] + n*64 + ((g ^ (n&7)) * 8));
            }
            #pragma unroll
            for (int fm = 0; fm < 4; ++fm)
                acc[fm] = __builtin_amdgcn_mfma_f32_16x16x32_bf16(a[fm], b, acc[fm], 0,0,0);
        }
        __builtin_amdgcn_s_setprio(0);
        if (t < 11) {
            #pragma unroll
            for (int s = 0; s < 2; ++s) {
                int idx = tid + s*256;
                int r = idx >> 3, c8 = idx & 7;
                unsigned int us32[4] = { pack2bf(rf[s][0].x, rf[s][0].y), pack2bf(rf[s][0].z, rf[s][0].w),
                                         pack2bf(rf[s][1].x, rf[s][1].y), pack2bf(rf[s][1].z, rf[s][1].w) };
                *(ushort8_t*)(fl[cur^1] + r*72 + c8*8) = *(ushort8_t*)us32;
            }
        }
        __syncthreads();
    }
    #pragma unroll
    for (int fm = 0; fm < 4; ++fm)
        #pragma unroll
        for (int q = 0; q < 4; ++q) {
            int row = m0 + fm*16 + (lane>>4)*4 + q;
            int col = n0 + wid*16 + (lane&15);
            float bias = (col < 768) ? b1[col] : 0.0f;
            AB[(size_t)row*1536 + col] = acc[fm][q] + bias;
        }
}

// ---------------- fused pair MLP: 1024 thr / 16 waves (4 per SIMD, 128-reg budget)
// W2/W3 B-frags global->VGPR (single-buffered; TLP hides L2 latency).
// Only h1/h2 route through LDS. phase A grid 2x8 (tile 64x48); phase B 4x4 (32x32)
__launch_bounds__(1024, 4)
__global__ void fused_k(const float* __restrict__ AB,            // [256][1536] f32
                        const unsigned short* __restrict__ W2t,  // [384][768] bf16
                        const float* __restrict__ b2,            // [384]
                        const unsigned short* __restrict__ W3t,  // [128][384] bf16
                        const float* __restrict__ b3,            // [128]
                        float* __restrict__ out) {               // [32640][128] f32
    __shared__ alignas(1024) char smem[100352];
    unsigned short* h1_0 = (unsigned short*)(smem);           // [128][72] buf 0
    unsigned short* h1_1 = (unsigned short*)(smem + 18432);   // [128][72] buf 1
    unsigned short* h2   = (unsigned short*)(smem);           // [128][392] phase B (reuse)

    int tid = threadIdx.x;
    int lane = tid & 63, wid = tid >> 6;   // 16 waves
    int wr = wid >> 3, wc = wid & 7;       // phase A: 2 x 8 wave grid
    int p0 = blockIdx.x * 128;

    // per-thread pair indices for my h1-gen row (8 threads per row)
    int hr = tid >> 3;                     // 0..127
    int hc = (tid & 7) * 8;                // col chunk within 64
    int p = p0 + hr;
    float sdisc = sqrtf((float)(511*511 - 8*p));
    int i_me = (int)((511.0f - sdisc) * 0.5f);
    if (i_me < 0) i_me = 0; if (i_me > 254) i_me = 254;
    while (i_me < 255 && (i_me+1)*255 - (i_me+1)*i_me/2 <= p) ++i_me;
    while (i_me > 0 && i_me*255 - i_me*(i_me-1)/2 > p) --i_me;
    int j_me = i_me + 1 + (p - (i_me*255 - i_me*(i_me-1)/2));

    const float* abI = AB + (size_t)i_me*1536 + hc;
    const float* abJ = AB + (size_t)j_me*1536 + 768 + hc;
    const unsigned short* w2p = W2t + (size_t)(wc*48 + (lane&15))*768 + (lane>>4)*8;

    float4 ra0, ra1, rb0, rb1;
    bf16x8 bfr[3][2];
    f32x4 acc2[4][3] = {};

#define H1_LOAD(KKN) { \
    const float4* pa_ = (const float4*)(abI + (KKN)); \
    const float4* pb_ = (const float4*)(abJ + (KKN)); \
    ra0 = pa_[0]; ra1 = pa_[1]; rb0 = pb_[0]; rb1 = pb_[1]; }

#define H1_PACK(H1N) { \
    unsigned int us32_[4] = { \
        pack2bf(fmaxf(ra0.x + rb0.x, 0.f), fmaxf(ra0.y + rb0.y, 0.f)), \
        pack2bf(fmaxf(ra0.z + rb0.z, 0.f), fmaxf(ra0.w + rb0.w, 0.f)), \
        pack2bf(fmaxf(ra1.x + rb1.x, 0.f), fmaxf(ra1.y + rb1.y, 0.f)), \
        pack2bf(fmaxf(ra1.z + rb1.z, 0.f), fmaxf(ra1.w + rb1.w, 0.f)) }; \
    *(ushort8_t*)((H1N) + hr*72 + hc) = *(ushort8_t*)us32_; }

#define PREFETCH_B(KKN) { \
    _Pragma("unroll") for (int fn_ = 0; fn_ < 3; ++fn_) \
    _Pragma("unroll") for (int ks_ = 0; ks_ < 2; ++ks_) \
        bfr[fn_][ks_] = *(const bf16x8*)(w2p + fn_*(16*768) + (KKN) + ks_*32); }

#define MFMA_A(H1C) { \
    __builtin_amdgcn_s_setprio(1); \
    _Pragma("unroll") for (int ks_ = 0; ks_ < 2; ++ks_) { \
        bf16x8 a_[4]; \
        _Pragma("unroll") for (int fm_ = 0; fm_ < 4; ++fm_) \
            a_[fm_] = *(const bf16x8*)((H1C) + (wr*64 + fm_*16 + (lane&15))*72 + ks_*32 + (lane>>4)*8); \
        _Pragma("unroll") for (int fm_ = 0; fm_ < 4; ++fm_) \
        _Pragma("unroll") for (int fn_ = 0; fn_ < 3; ++fn_) \
            acc2[fm_][fn_] = __builtin_amdgcn_mfma_f32_16x16x32_bf16(a_[fm_], bfr[fn_][ks_], acc2[fm_][fn_], 0,0,0); } \
    __builtin_amdgcn_s_setprio(0); }

#define BAR() { asm volatile("s_waitcnt lgkmcnt(0)" ::: "memory"); \
    __builtin_amdgcn_sched_barrier(0); __builtin_amdgcn_s_barrier(); }

    // ---- prologue: h1(0)
    H1_LOAD(0);
    H1_PACK(h1_0);
    BAR();

    // ---- phase A: 12 K-steps; b-frags reloaded each step (single buffer)
    #pragma unroll 2
    for (int t = 0; t < 11; ++t) {
        unsigned short* h1c = (t & 1) ? h1_1 : h1_0;
        unsigned short* h1n = (t & 1) ? h1_0 : h1_1;
        H1_LOAD((t+1) * 64);               // AB(t+1) first (oldest in queue)
        PREFETCH_B(t * 64);                // b(t) after (MFMA waits these)
        MFMA_A(h1c);                       // AB(t+1) lands during MFMA
        H1_PACK(h1n);
        BAR();
    }
    {   // t=11: no next-step loads
        PREFETCH_B(11 * 64);
        MFMA_A(h1_1);
        BAR();                             // all h1 reads done -> reuse as h2
    }

    // ---- phase B: 4x4 wave grid, tile 32x32; W3 frags global->VGPR (dbuf fits)
    int wrB = wid >> 2, wcB = wid & 3;
    const unsigned short* w3p = W3t + (size_t)(wcB*32 + (lane&15))*384 + (lane>>4)*8;
    bf16x8 wA[2][2], wB[2][2];
    f32x4 acc3[2][2] = {};

#define PREFETCH_W3(WP, KT) { \
    _Pragma("unroll") for (int fn_ = 0; fn_ < 2; ++fn_) \
    _Pragma("unroll") for (int ks_ = 0; ks_ < 2; ++ks_) \
        WP[fn_][ks_] = *(const bf16x8*)(w3p + fn_*(16*384) + (KT)*64 + ks_*32); }

#define MFMA_B(WU, KT) { \
    __builtin_amdgcn_s_setprio(1); \
    _Pragma("unroll") for (int ks_ = 0; ks_ < 2; ++ks_) { \
        bf16x8 a_[2]; \
        _Pragma("unroll") for (int fm_ = 0; fm_ < 2; ++fm_) \
            a_[fm_] = *(const bf16x8*)(h2 + (wrB*32 + fm_*16 + (lane&15))*392 + (KT)*64 + ks_*32 + (lane>>4)*8); \
        _Pragma("unroll") for (int fm_ = 0; fm_ < 2; ++fm_) \
        _Pragma("unroll") for (int fn_ = 0; fn_ < 2; ++fn_) \
            acc3[fm_][fn_] = __builtin_amdgcn_mfma_f32_16x16x32_bf16(a_[fm_], WU[fn_][ks_], acc3[fm_][fn_], 0,0,0); } \
    __builtin_amdgcn_s_setprio(0); }

    PREFETCH_W3(wA, 0);
    // h2 = relu(acc2 + b2) -> LDS [128][392]
    #pragma unroll
    for (int fn = 0; fn < 3; ++fn) {
        int col = wc*48 + fn*16 + (lane&15);
        float bb = b2[col];
        #pragma unroll
        for (int fm = 0; fm < 4; ++fm)
            #pragma unroll
            for (int q = 0; q < 4; ++q) {
                int row = wr*64 + fm*16 + (lane>>4)*4 + q;
                h2[row*392 + col] = f2bf1(fmaxf(acc2[fm][fn][q] + bb, 0.f));
            }
    }
    BAR();                                  // h2 visible; w3(0) still in flight

    // ---- phase B: 6 K-steps, barrier-free, fully unrolled even/odd
    PREFETCH_W3(wB, 1); MFMA_B(wA, 0);
    PREFETCH_W3(wA, 2); MFMA_B(wB, 1);
    PREFETCH_W3(wB, 3); MFMA_B(wA, 2);
    PREFETCH_W3(wA, 4); MFMA_B(wB, 3);
    PREFETCH_W3(wB, 5); MFMA_B(wA, 4);
    MFMA_B(wB, 5);

    #pragma unroll
    for (int fm = 0; fm < 2; ++fm)
        #pragma unroll
        for (int fn = 0; fn < 2; ++fn) {
            int col = wcB*32 + fn*16 + (lane&15);
            float bb = b3[col];
            #pragma unroll
            for (int q = 0; q < 4; ++q) {
                int row = p0 + wrB*32 + fm*16 + (lane>>4)*4 + q;
                out[(size_t)row*128 + col] = acc3[fm][fn][q] + bb;
            }
        }
}

extern "C" void kernel_launch(void* const* d_in, const int* in_sizes, int n_in,
                              void* d_out, int out_size, void* d_ws, size_t ws_size,
                              hipStream_t stream) {
    const float* feat = (const float*)d_in[0];  // [256][768]
    const float* W1   = (const float*)d_in[1];  // [1536][768]
    const float* b1   = (const float*)d_in[2];  // [768]
    const float* W2   = (const float*)d_in[3];  // [768][384]
    const float* b2   = (const float*)d_in[4];  // [384]
    const float* W3   = (const float*)d_in[5];  // [384][128]
    const float* b3   = (const float*)d_in[6];  // [128]
    float* out = (float*)d_out;

    char* ws = (char*)d_ws;
    unsigned short* W1x = (unsigned short*)(ws + 0);        // 1536*768*2 = 2,359,296
    unsigned short* W2t = (unsigned short*)(ws + 2359296);  // 384*768*2  =   589,824
    unsigned short* W3t = (unsigned short*)(ws + 2949120);  // 128*384*2  =    98,304
    float*          AB  = (float*)        (ws + 3047424);   // 256*1536*4 = 1,572,864

    prep_k<<<1488, dim3(32,8), 0, stream>>>(W1, W2, W3, W1x, W2t, W3t);
    ab_gemm_k<<<dim3(24,4), 256, 0, stream>>>(feat, W1x, b1, AB);
    fused_k<<<255, 1024, 0, stream>>>(AB, W2t, b2, W3t, b3, out);
}

// Round 9
// 56.285 us; speedup vs baseline: 1.4829x; 1.4829x over previous
//
#include <hip/hip_runtime.h>
#include <hip/hip_bf16.h>
#include <stdint.h>

#define HID 768

typedef short bf16x8 __attribute__((ext_vector_type(8)));
typedef unsigned short ushort8_t __attribute__((ext_vector_type(8)));
typedef float f32x4 __attribute__((ext_vector_type(4)));

// packed f32x2 -> bf16x2 (compiler emits v_cvt_pk_bf16_f32)
__device__ __forceinline__ unsigned int pack2bf(float x, float y) {
    __hip_bfloat162 h = __float22bfloat162_rn(make_float2(x, y));
    return *reinterpret_cast<unsigned int*>(&h);
}
__device__ __forceinline__ unsigned short f2bf1(float x) {
    __hip_bfloat16 h = __float2bfloat16(x);
    return *reinterpret_cast<unsigned short*>(&h);
}

// async global->LDS, 16B per lane; lds dest = wave-uniform base + lane*16
__device__ __forceinline__ void gload_lds16(const void* g, void* l) {
    __builtin_amdgcn_global_load_lds(
        (const __attribute__((address_space(1))) unsigned int*)g,
        (__attribute__((address_space(3))) unsigned int*)l, 16, 0, 0);
}

// ---------------- merged transpose+cast: 4 regions, f32 [R][C] -> bf16 [C][R] ----
__global__ void prep_k(const float* __restrict__ W1,
                       const float* __restrict__ W2,
                       const float* __restrict__ W3,
                       unsigned short* __restrict__ W1x,
                       unsigned short* __restrict__ W2t,
                       unsigned short* __restrict__ W3t) {
    __shared__ float t[32][33];
    int b = blockIdx.x;
    const float* in; unsigned short* op; int R, C, bx, by;
    if (b < 576)       { in = W1;           op = W1x;           R = 768; C = 768; bx = b % 24;        by = b / 24; }
    else if (b < 1152) { in = W1 + 768*768; op = W1x + 768*768; R = 768; C = 768; bx = (b-576) % 24;  by = (b-576) / 24; }
    else if (b < 1440) { in = W2;           op = W2t;           R = 768; C = 384; bx = (b-1152) % 12; by = (b-1152) / 12; }
    else               { in = W3;           op = W3t;           R = 384; C = 128; bx = (b-1440) % 4;  by = (b-1440) / 4; }
    int c0 = bx * 32, r0 = by * 32;
    int tx = threadIdx.x, ty = threadIdx.y;   // 32 x 8
    #pragma unroll
    for (int k = 0; k < 4; ++k)
        t[ty + 8*k][tx] = in[(size_t)(r0 + ty + 8*k) * C + c0 + tx];
    __syncthreads();
    #pragma unroll
    for (int k = 0; k < 4; ++k)
        op[(size_t)(c0 + ty + 8*k) * R + r0 + tx] = f2bf1(t[tx][ty + 8*k]);
}

// ---------------- AB = feat @ W1x^T (+b1 on A half) : M=256, N=1536, K=768 ------
// 96 blocks of 64m x 64n; 4 waves, wave n-band = wid*16
__launch_bounds__(256, 2)
__global__ void ab_gemm_k(const float* __restrict__ F,
                          const unsigned short* __restrict__ W,
                          const float* __restrict__ b1,
                          float* __restrict__ AB) {
    __shared__ alignas(1024) unsigned short fl[2][64*72];   // 18,432 B
    __shared__ alignas(1024) unsigned short wl[2][64*64];   // 16,384 B (swizzled)
    int tid = threadIdx.x;
    int lane = tid & 63, wid = tid >> 6;   // 4 waves
    int n0 = blockIdx.x * 64, m0 = blockIdx.y * 64;
    f32x4 acc[4] = {};
    float4 rf[2][2];

    #pragma unroll
    for (int s = 0; s < 2; ++s) {          // W tile 64x64 -> 8 chunks of 1024B
        int chunk = wid*2 + s;
        int row = chunk*8 + (lane>>3);
        int cg = (lane&7) ^ (row&7);
        gload_lds16(W + (size_t)(n0 + row)*HID + cg*8, (char*)wl[0] + chunk*1024);
    }
    #pragma unroll
    for (int s = 0; s < 2; ++s) {          // F tile 64x64 f32
        int idx = tid + s*256;
        int r = idx >> 3, c8 = idx & 7;
        const float4* src = (const float4*)(F + (size_t)(m0 + r)*HID + c8*8);
        rf[s][0] = src[0]; rf[s][1] = src[1];
    }
    #pragma unroll
    for (int s = 0; s < 2; ++s) {
        int idx = tid + s*256;
        int r = idx >> 3, c8 = idx & 7;
        unsigned int us32[4] = { pack2bf(rf[s][0].x, rf[s][0].y), pack2bf(rf[s][0].z, rf[s][0].w),
                                 pack2bf(rf[s][1].x, rf[s][1].y), pack2bf(rf[s][1].z, rf[s][1].w) };
        *(ushort8_t*)(fl[0] + r*72 + c8*8) = *(ushort8_t*)us32;
    }
    __syncthreads();

    for (int t = 0; t < 12; ++t) {
        int cur = t & 1;
        if (t < 11) {
            int kk = (t+1) * 64;
            #pragma unroll
            for (int s = 0; s < 2; ++s) {
                int chunk = wid*2 + s;
                int row = chunk*8 + (lane>>3);
                int cg = (lane&7) ^ (row&7);
                gload_lds16(W + (size_t)(n0 + row)*HID + kk + cg*8, (char*)wl[cur^1] + chunk*1024);
            }
            #pragma unroll
            for (int s = 0; s < 2; ++s) {
                int idx = tid + s*256;
                int r = idx >> 3, c8 = idx & 7;
                const float4* src = (const float4*)(F + (size_t)(m0 + r)*HID + kk + c8*8);
                rf[s][0] = src[0]; rf[s][1] = src[1];
            }
        }
        __builtin_amdgcn_s_setprio(1);
        #pragma unroll
        for (int ks = 0; ks < 2; ++ks) {
            bf16x8 a[4], b;
            #pragma unroll
            for (int fm = 0; fm < 4; ++fm)
                a[fm] = *(const bf16x8*)(fl[cur] + (fm*16 + (lane&15))*72 + ks*32 + (lane>>4)*8);
            {
                int n = wid*16 + (lane&15);
                int g = ks*4 + (lane>>4);
                b = *(const bf16x8*)(wl[cur] + n*64 + ((g ^ (n&7)) * 8));
            }
            #pragma unroll
            for (int fm = 0; fm < 4; ++fm)
                acc[fm] = __builtin_amdgcn_mfma_f32_16x16x32_bf16(a[fm], b, acc[fm], 0,0,0);
        }
        __builtin_amdgcn_s_setprio(0);
        if (t < 11) {
            #pragma unroll
            for (int s = 0; s < 2; ++s) {
                int idx = tid + s*256;
                int r = idx >> 3, c8 = idx & 7;
                unsigned int us32[4] = { pack2bf(rf[s][0].x, rf[s][0].y), pack2bf(rf[s][0].z, rf[s][0].w),
                                         pack2bf(rf[s][1].x, rf[s][1].y), pack2bf(rf[s][1].z, rf[s][1].w) };
                *(ushort8_t*)(fl[cur^1] + r*72 + c8*8) = *(ushort8_t*)us32;
            }
        }
        __syncthreads();
    }
    #pragma unroll
    for (int fm = 0; fm < 4; ++fm)
        #pragma unroll
        for (int q = 0; q < 4; ++q) {
            int row = m0 + fm*16 + (lane>>4)*4 + q;
            int col = n0 + wid*16 + (lane&15);
            float bias = (col < 768) ? b1[col] : 0.0f;
            AB[(size_t)row*1536 + col] = acc[fm][q] + bias;
        }
}

// ---------------- fused pair MLP: 64 pairs/block, 510 blocks, 2 blocks/CU -------
// 512 thr = 8 waves. Phase A grid 1x8 (wave tile 64x48); w2 single-buf gload_lds;
// h1 dbuf. Phase B grid 2x4 (32x32); w3 single-buf. Sibling block hides stalls.
__launch_bounds__(512, 4)
__global__ void fused_k(const float* __restrict__ AB,            // [256][1536] f32
                        const unsigned short* __restrict__ W2t,  // [384][768] bf16
                        const float* __restrict__ b2,            // [384]
                        const unsigned short* __restrict__ W3t,  // [128][384] bf16
                        const float* __restrict__ b3,            // [128]
                        float* __restrict__ out) {               // [32640][128] f32
    __shared__ alignas(1024) char smem[67584];
    unsigned short* h1_0 = (unsigned short*)(smem);           // [64][72]  (9,216 B)
    unsigned short* h1_1 = (unsigned short*)(smem + 9216);    // [64][72]
    unsigned short* w2   = (unsigned short*)(smem + 18432);   // [384][64] swizzled (49,152 B)
    unsigned short* h2   = (unsigned short*)(smem);           // [64][392] phase B  (50,176 B)
    unsigned short* w3   = (unsigned short*)(smem + 50176);   // [128][64] swizzled (16,384 B)

    int tid = threadIdx.x;
    int lane = tid & 63, wid = tid >> 6;   // 8 waves
    int wc = wid;                          // phase A: 1 x 8 wave grid, tile 64 x 48
    int p0 = blockIdx.x * 64;

    // per-thread pair indices for my h1-gen row (8 threads per row)
    int hr = tid >> 3;                     // 0..63
    int hc = (tid & 7) * 8;                // col chunk within 64
    int p = p0 + hr;
    float sdisc = sqrtf((float)(511*511 - 8*p));
    int i_me = (int)((511.0f - sdisc) * 0.5f);
    if (i_me < 0) i_me = 0; if (i_me > 254) i_me = 254;
    while (i_me < 255 && (i_me+1)*255 - (i_me+1)*i_me/2 <= p) ++i_me;
    while (i_me > 0 && i_me*255 - i_me*(i_me-1)/2 > p) --i_me;
    int j_me = i_me + 1 + (p - (i_me*255 - i_me*(i_me-1)/2));

    const float* abI = AB + (size_t)i_me*1536 + hc;
    const float* abJ = AB + (size_t)j_me*1536 + 768 + hc;

    float4 ra0, ra1, rb0, rb1;
    f32x4 acc2[4][3] = {};

#define H1_LOAD(KKN) { \
    const float4* pa_ = (const float4*)(abI + (KKN)); \
    const float4* pb_ = (const float4*)(abJ + (KKN)); \
    ra0 = pa_[0]; ra1 = pa_[1]; rb0 = pb_[0]; rb1 = pb_[1]; }

#define H1_PACK(H1N) { \
    unsigned int us32_[4] = { \
        pack2bf(fmaxf(ra0.x + rb0.x, 0.f), fmaxf(ra0.y + rb0.y, 0.f)), \
        pack2bf(fmaxf(ra0.z + rb0.z, 0.f), fmaxf(ra0.w + rb0.w, 0.f)), \
        pack2bf(fmaxf(ra1.x + rb1.x, 0.f), fmaxf(ra1.y + rb1.y, 0.f)), \
        pack2bf(fmaxf(ra1.z + rb1.z, 0.f), fmaxf(ra1.w + rb1.w, 0.f)) }; \
    *(ushort8_t*)((H1N) + hr*72 + hc) = *(ushort8_t*)us32_; }

#define MFMA_A(H1C) { \
    __builtin_amdgcn_s_setprio(1); \
    _Pragma("unroll") for (int ks_ = 0; ks_ < 2; ++ks_) { \
        bf16x8 a_[4], b_[3]; \
        _Pragma("unroll") for (int fm_ = 0; fm_ < 4; ++fm_) \
            a_[fm_] = *(const bf16x8*)((H1C) + (fm_*16 + (lane&15))*72 + ks_*32 + (lane>>4)*8); \
        _Pragma("unroll") for (int fn_ = 0; fn_ < 3; ++fn_) { \
            int n_ = wc*48 + fn_*16 + (lane&15); \
            int g_ = ks_*4 + (lane>>4); \
            b_[fn_] = *(const bf16x8*)(w2 + n_*64 + ((g_ ^ (n_&7)) * 8)); } \
        _Pragma("unroll") for (int fm_ = 0; fm_ < 4; ++fm_) \
        _Pragma("unroll") for (int fn_ = 0; fn_ < 3; ++fn_) \
            acc2[fm_][fn_] = __builtin_amdgcn_mfma_f32_16x16x32_bf16(a_[fm_], b_[fn_], acc2[fm_][fn_], 0,0,0); } \
    __builtin_amdgcn_s_setprio(0); }

#define BAR() { asm volatile("s_waitcnt lgkmcnt(0)" ::: "memory"); \
    __builtin_amdgcn_sched_barrier(0); __builtin_amdgcn_s_barrier(); }

    // ---- prologue: h1(0)
    H1_LOAD(0);
    H1_PACK(h1_0);
    BAR();

    // ---- phase A: 12 K-steps; w2 single-buffered, staged per step
    for (int t = 0; t < 12; ++t) {
        unsigned short* h1c = (t & 1) ? h1_1 : h1_0;
        unsigned short* h1n = (t & 1) ? h1_0 : h1_1;
        // stage w2(t): 48 chunks of 1024B, 6 per wave (prev readers done at last BAR)
        #pragma unroll
        for (int s = 0; s < 6; ++s) {
            int chunk = wid*6 + s;
            int row = chunk*8 + (lane>>3);
            int cg = (lane&7) ^ (row&7);
            gload_lds16(W2t + (size_t)row*HID + t*64 + cg*8, (char*)w2 + chunk*1024);
        }
        if (t < 11) {
            H1_LOAD((t+1) * 64);           // 4 AB loads, newer than the 6 gloads
            asm volatile("s_waitcnt vmcnt(4)" ::: "memory");   // w2(t) landed
        } else {
            asm volatile("s_waitcnt vmcnt(0)" ::: "memory");
        }
        __builtin_amdgcn_sched_barrier(0);
        __builtin_amdgcn_s_barrier();      // all w2(t) writes visible
        MFMA_A(h1c);
        if (t < 11) H1_PACK(h1n);
        BAR();                             // h1(t+1) visible; w2 readers done
    }

    // ---- phase B: h2 = relu(acc2+b2) -> [64][392]; w3 single-buf; grid 2x4
    #pragma unroll
    for (int fn = 0; fn < 3; ++fn) {
        int col = wc*48 + fn*16 + (lane&15);
        float bb = b2[col];
        #pragma unroll
        for (int fm = 0; fm < 4; ++fm)
            #pragma unroll
            for (int q = 0; q < 4; ++q) {
                int row = fm*16 + (lane>>4)*4 + q;
                h2[row*392 + col] = f2bf1(fmaxf(acc2[fm][fn][q] + bb, 0.f));
            }
    }

    int wrB = wid >> 2, wcB = wid & 3;     // 2 x 4 wave grid, tile 32 x 32
    f32x4 acc3[2][2] = {};
    for (int kt = 0; kt < 6; ++kt) {
        // stage w3(kt): 16 chunks, 2 per wave (prev readers done at last BAR;
        // kt=0: w2-region readers done at phase-A tail BAR)
        #pragma unroll
        for (int s = 0; s < 2; ++s) {
            int chunk = wid*2 + s;
            int row = chunk*8 + (lane>>3);
            int cg = (lane&7) ^ (row&7);
            gload_lds16(W3t + (size_t)row*384 + kt*64 + cg*8, (char*)w3 + chunk*1024);
        }
        asm volatile("s_waitcnt vmcnt(0)" ::: "memory");
        BAR();                             // w3(kt) + (kt=0: h2) visible
        __builtin_amdgcn_s_setprio(1);
        #pragma unroll
        for (int ks = 0; ks < 2; ++ks) {
            bf16x8 a[2], b[2];
            #pragma unroll
            for (int fm = 0; fm < 2; ++fm)
                a[fm] = *(const bf16x8*)(h2 + (wrB*32 + fm*16 + (lane&15))*392 + kt*64 + ks*32 + (lane>>4)*8);
            #pragma unroll
            for (int fn = 0; fn < 2; ++fn) {
                int n = wcB*32 + fn*16 + (lane&15);
                int g = ks*4 + (lane>>4);
                b[fn] = *(const bf16x8*)(w3 + n*64 + ((g ^ (n&7)) * 8));
            }
            #pragma unroll
            for (int fm = 0; fm < 2; ++fm)
                #pragma unroll
                for (int fn = 0; fn < 2; ++fn)
                    acc3[fm][fn] = __builtin_amdgcn_mfma_f32_16x16x32_bf16(a[fm], b[fn], acc3[fm][fn], 0,0,0);
        }
        __builtin_amdgcn_s_setprio(0);
        BAR();                             // w3 readers done -> next stage safe
    }

    #pragma unroll
    for (int fm = 0; fm < 2; ++fm)
        #pragma unroll
        for (int fn = 0; fn < 2; ++fn) {
            int col = wcB*32 + fn*16 + (lane&15);
            float bb = b3[col];
            #pragma unroll
            for (int q = 0; q < 4; ++q) {
                int row = p0 + wrB*32 + fm*16 + (lane>>4)*4 + q;
                out[(size_t)row*128 + col] = acc3[fm][fn][q] + bb;
            }
        }
}

extern "C" void kernel_launch(void* const* d_in, const int* in_sizes, int n_in,
                              void* d_out, int out_size, void* d_ws, size_t ws_size,
                              hipStream_t stream) {
    const float* feat = (const float*)d_in[0];  // [256][768]
    const float* W1   = (const float*)d_in[1];  // [1536][768]
    const float* b1   = (const float*)d_in[2];  // [768]
    const float* W2   = (const float*)d_in[3];  // [768][384]
    const float* b2   = (const float*)d_in[4];  // [384]
    const float* W3   = (const float*)d_in[5];  // [384][128]
    const float* b3   = (const float*)d_in[6];  // [128]
    float* out = (float*)d_out;

    char* ws = (char*)d_ws;
    unsigned short* W1x = (unsigned short*)(ws + 0);        // 1536*768*2 = 2,359,296
    unsigned short* W2t = (unsigned short*)(ws + 2359296);  // 384*768*2  =   589,824
    unsigned short* W3t = (unsigned short*)(ws + 2949120);  // 128*384*2  =    98,304
    float*          AB  = (float*)        (ws + 3047424);   // 256*1536*4 = 1,572,864

    prep_k<<<1488, dim3(32,8), 0, stream>>>(W1, W2, W3, W1x, W2t, W3t);
    ab_gemm_k<<<dim3(24,4), 256, 0, stream>>>(feat, W1x, b1, AB);
    fused_k<<<510, 512, 0, stream>>>(AB, W2t, b2, W3t, b3, out);
}